// Round 5
// baseline (324.671 us; speedup 1.0000x reference)
//
#include <hip/hip_runtime.h>

#define NQv 20000
#define NSv 8192
#define Cv  112
#define CLSv 20
#define INFF 3.4e38f

#define POOLB 64
#define PT 256
#define PPB (POOLB + NSv / PT)      // 64 pool blocks + 32 pts blocks = 96
#define PNW (POOLB * PT / 64)       // 256 pool waves

#define MT 256
#define QT 32
#define MB (NQv / QT)               // 625 (exact)
#define VP 36
#define WS_PTS 8192                 // float offset of float4 pts table in ws (16B aligned)

// ---- prep: pool partials (blocks 0..63) + point table (blocks 64..95)
__global__ __launch_bounds__(PT) void k_prep(const float* __restrict__ cs,
                                             const float* __restrict__ fs7,
                                             const float* __restrict__ wat,
                                             float* __restrict__ ws) {
    int b = blockIdx.x;
    if (b >= POOLB) {               // pts: (-2x,-2y,-2z,|s|^2), one point per thread
        int p = (b - POOLB) * PT + threadIdx.x;
        float x = cs[3 * p], y = cs[3 * p + 1], z = cs[3 * p + 2];
        ((float4*)(ws + WS_PTS))[p] =
            make_float4(-2.f * x, -2.f * y, -2.f * z, fmaf(x, x, fmaf(y, y, z * z)));
        return;
    }
    __shared__ float red[PT / 64][Cv + 1];
    int tid = b * PT + threadIdx.x;
    int wid = tid >> 6, lw = threadIdx.x >> 6, lane = tid & 63, l2 = lane * 2;
    float2 wa = make_float2(0.f, 0.f);
    if (lane < 56) wa = *(const float2*)(wat + l2);
    float gx = 0.f, gy = 0.f, z = 0.f;
    for (int i = wid; i < NSv; i += PNW) {          // 32 rows per wave
        float2 f = make_float2(0.f, 0.f);
        if (lane < 56) f = *(const float2*)(fs7 + i * Cv + l2);
        float part = f.x * wa.x + f.y * wa.y;
        #pragma unroll
        for (int off = 32; off; off >>= 1) part += __shfl_xor(part, off, 64);
        float p = __expf(part);                     // |logit| small, f32-safe
        gx = fmaf(p, f.x, gx); gy = fmaf(p, f.y, gy); z += p;
    }
    if (lane < 56) { red[lw][l2] = gx; red[lw][l2 + 1] = gy; }
    if (lane == 0) red[lw][Cv] = z;
    __syncthreads();
    int t = threadIdx.x;
    if (t < Cv + 1)
        ws[b * (Cv + 1) + t] = red[0][t] + red[1][t] + red[2][t] + red[3][t];
}

// ---- fused: SMEM-streamed scan (top-3) + gate + batched MLP GEMM, 32 queries/block
__global__ __launch_bounds__(MT) void k_fused(
        const float* __restrict__ cq, const float* __restrict__ x7,
        const float* __restrict__ fs, const float* __restrict__ W1,
        const float* __restrict__ gma, const float* __restrict__ bta,
        const float* __restrict__ W2, const float* __restrict__ Wc,
        const float* __restrict__ bc, const float* __restrict__ ws,
        float* __restrict__ out) {
    __shared__ float big[224 * VP];          // scan cands (aliased) -> V^T -> h2^T
    __shared__ float tT[Cv * VP];            // h1 post-BN-ReLU, transposed
    __shared__ float gate[Cv];
    __shared__ int   qi[QT][3];
    __shared__ float qw[QT][3];
    float* cand_e = big;                     // [4 waves][64 lanes][3]
    int*   cand_j = (int*)(big + 768);

    const float4* __restrict__ ptsg = (const float4*)(ws + WS_PTS);
    int tid = threadIdx.x;
    int q0 = blockIdx.x * QT;

    if (tid < Cv) {                          // gate = sigmoid(pooled mean)
        float st = 0.f, zt = 0.f;
        for (int b = 0; b < POOLB; ++b) {
            st += ws[b * (Cv + 1) + tid];
            zt += ws[b * (Cv + 1) + Cv];
        }
        gate[tid] = 1.0f / (1.0f + __expf(-(st / zt)));
    }

    int lane = tid & 63, widx = tid >> 6;
    int qsub = lane & 31, h = lane >> 5;
    int q = q0 + qsub;
    float qx = cq[3 * q], qy = cq[3 * q + 1], qz = cq[3 * q + 2];

    // scan: e = |s|^2 - 2 q.s  (q^2 cancels in softmax). Wave widx covers points
    // [widx*2048, widx*2048+2048); half-lanes split it 1024/1024. Point data is
    // wave-uniform -> scalar (SMEM) loads; zero LDS traffic in the loop.
    int sbase = widx * 2048;
    int pbase = sbase + (h << 10);
    float e0 = INFF, e1 = INFF, e2 = INFF;
    int   j0 = 0x7fffffff, j1 = 0x7fffffff, j2 = 0x7fffffff;
    #pragma unroll 4
    for (int k = 0; k < 1024; ++k) {
        float4 Pa = ptsg[sbase + k];                // uniform -> s_load_dwordx4
        float4 Pb = ptsg[sbase + 1024 + k];         // uniform -> s_load_dwordx4
        float ea = fmaf(qx, Pa.x, fmaf(qy, Pa.y, fmaf(qz, Pa.z, Pa.w)));
        float eb = fmaf(qx, Pb.x, fmaf(qy, Pb.y, fmaf(qz, Pb.z, Pb.w)));
        float e  = h ? eb : ea;
        if (__any(e < e2)) {
            bool c2 = e < e2, c1 = e < e1, c0 = e < e0;
            int pj = pbase + k;
            e2 = c1 ? e1 : (c2 ? e : e2);  j2 = c1 ? j1 : (c2 ? pj : j2);
            e1 = c0 ? e0 : (c1 ? e : e1);  j1 = c0 ? j0 : (c1 ? pj : j1);
            e0 = c0 ? e  : e0;             j0 = c0 ? pj : j0;
        }
    }
    {   // deposit per-lane top-3 candidates
        int base = (widx * 64 + lane) * 3;
        cand_e[base] = e0; cand_e[base + 1] = e1; cand_e[base + 2] = e2;
        cand_j[base] = j0; cand_j[base + 1] = j1; cand_j[base + 2] = j2;
    }
    __syncthreads();

    // merge 24 candidates per query, lex (e, idx) = jax top_k tie semantics
    if (tid < QT) {
        float E0 = INFF, E1 = INFF, E2 = INFF;
        int   J0 = 0x7fffffff, J1 = 0x7fffffff, J2 = 0x7fffffff;
        for (int w = 0; w < 4; ++w)
            #pragma unroll
            for (int hh = 0; hh < 2; ++hh) {
                int base = (w * 64 + tid + 32 * hh) * 3;
                #pragma unroll
                for (int r = 0; r < 3; ++r) {
                    float e = cand_e[base + r]; int jj = cand_j[base + r];
                    bool lt2 = (e < E2) || (e == E2 && jj < J2);
                    if (lt2) {
                        bool lt1 = (e < E1) || (e == E1 && jj < J1);
                        bool lt0 = (e < E0) || (e == E0 && jj < J0);
                        E2 = lt1 ? E1 : e;              J2 = lt1 ? J1 : jj;
                        E1 = lt0 ? E0 : (lt1 ? e : E1); J1 = lt0 ? J0 : (lt1 ? jj : J1);
                        if (lt0) { E0 = e; J0 = jj; }
                    }
                }
            }
        float w1v = __expf(E0 - E1);
        float w2v = __expf(E0 - E2);
        float iw  = 1.0f / (1.0f + w1v + w2v);
        qw[tid][0] = iw; qw[tid][1] = w1v * iw; qw[tid][2] = w2v * iw;
        qi[tid][0] = (J0 < 0 || J0 >= NSv) ? 0 : J0;
        qi[tid][1] = (J1 < 0 || J1 >= NSv) ? 0 : J1;
        qi[tid][2] = (J2 < 0 || J2 >= NSv) ? 0 : J2;
    }
    __syncthreads();

    // build V^T[224][VP]: rows 0..111 = gated x7, rows 112..223 = matched
    {
        int vq = tid >> 3, e8 = tid & 7;
        int gq = q0 + vq;
        int i0 = qi[vq][0], i1 = qi[vq][1], i2 = qi[vq][2];
        float w0 = qw[vq][0], w1v = qw[vq][1], w2v = qw[vq][2];
        #pragma unroll
        for (int r = 0; r < 14; ++r) {
            int k = e8 + (r << 3);
            float m = w0 * fs[i0 * Cv + k] + w1v * fs[i1 * Cv + k] + w2v * fs[i2 * Cv + k];
            big[k * VP + vq] = x7[gq * Cv + k] * gate[k];
            big[(Cv + k) * VP + vq] = m;
        }
    }
    __syncthreads();

    int tx = tid % 28, ty = tid / 28;        // 4 cols x 4 queries per thread, ty<8 active
    int cb = tx * 4, qb = ty * 4;

    // h1 = V @ W1 -> BN affine -> ReLU -> tT[c][q]
    if (ty < 8) {
        float acc[4][4] = {};
        #pragma unroll 4
        for (int k = 0; k < 2 * Cv; ++k) {
            float4 vv = *(const float4*)&big[k * VP + qb];
            float4 ww = *(const float4*)&W1[k * Cv + cb];
            #pragma unroll
            for (int i = 0; i < 4; ++i) {
                float v = (&vv.x)[i];
                acc[i][0] = fmaf(v, ww.x, acc[i][0]);
                acc[i][1] = fmaf(v, ww.y, acc[i][1]);
                acc[i][2] = fmaf(v, ww.z, acc[i][2]);
                acc[i][3] = fmaf(v, ww.w, acc[i][3]);
            }
        }
        #pragma unroll
        for (int j = 0; j < 4; ++j) {
            float g = gma[cb + j], b = bta[cb + j];
            #pragma unroll
            for (int i = 0; i < 4; ++i) {
                float hh = fmaf(acc[i][j], g, b);
                tT[(cb + j) * VP + qb + i] = hh > 0.f ? hh : 0.f;
            }
        }
    }
    __syncthreads();

    // h2 = t @ W2 -> big[c][q] (V^T dead)
    if (ty < 8) {
        float acc[4][4] = {};
        #pragma unroll 4
        for (int k = 0; k < Cv; ++k) {
            float4 vv = *(const float4*)&tT[k * VP + qb];
            float4 ww = *(const float4*)&W2[k * Cv + cb];
            #pragma unroll
            for (int i = 0; i < 4; ++i) {
                float v = (&vv.x)[i];
                acc[i][0] = fmaf(v, ww.x, acc[i][0]);
                acc[i][1] = fmaf(v, ww.y, acc[i][1]);
                acc[i][2] = fmaf(v, ww.z, acc[i][2]);
                acc[i][3] = fmaf(v, ww.w, acc[i][3]);
            }
        }
        #pragma unroll
        for (int j = 0; j < 4; ++j)
            #pragma unroll
            for (int i = 0; i < 4; ++i)
                big[(cb + j) * VP + qb + i] = acc[i][j];
    }
    __syncthreads();

    // out = h2 @ Wc + bc
    {
        int qq = tid & 31, cg = tid >> 5;
        int ob = cg * 3;
        if (ob < CLSv) {
            int nc = CLSv - ob; if (nc > 3) nc = 3;
            float a0 = bc[ob];
            float a1 = (nc > 1) ? bc[ob + 1] : 0.f;
            float a2 = (nc > 2) ? bc[ob + 2] : 0.f;
            #pragma unroll 4
            for (int k = 0; k < Cv; ++k) {
                float hh = big[k * VP + qq];
                a0 = fmaf(hh, Wc[k * CLSv + ob], a0);
                if (nc > 1) a1 = fmaf(hh, Wc[k * CLSv + ob + 1], a1);
                if (nc > 2) a2 = fmaf(hh, Wc[k * CLSv + ob + 2], a2);
            }
            float* o = out + (q0 + qq) * CLSv + ob;
            o[0] = a0;
            if (nc > 1) o[1] = a1;
            if (nc > 2) o[2] = a2;
        }
    }
}

extern "C" void kernel_launch(void* const* d_in, const int* in_sizes, int n_in,
                              void* d_out, int out_size, void* d_ws, size_t ws_size,
                              hipStream_t stream) {
    const float* cq  = (const float*)d_in[0];
    const float* cs  = (const float*)d_in[1];
    const float* x7  = (const float*)d_in[2];
    const float* fs7 = (const float*)d_in[3];
    const float* fs  = (const float*)d_in[4];
    const float* wat = (const float*)d_in[5];
    const float* W1  = (const float*)d_in[6];
    const float* gma = (const float*)d_in[7];
    const float* bta = (const float*)d_in[8];
    const float* W2  = (const float*)d_in[9];
    const float* Wc  = (const float*)d_in[10];
    const float* bc  = (const float*)d_in[11];
    float* ws  = (float*)d_ws;
    float* out = (float*)d_out;

    k_prep<<<PPB, PT, 0, stream>>>(cs, fs7, wat, ws);
    k_fused<<<MB, MT, 0, stream>>>(cq, x7, fs, W1, gma, bta, W2, Wc, bc, ws, out);
}

// Round 6
// 257.315 us; speedup vs baseline: 1.2618x; 1.2618x over previous
//
#include <hip/hip_runtime.h>

#define NQv 20000
#define NSv 8192
#define Cv  112
#define CLSv 20
#define INFF 3.4e38f
#define JINF 0x7fffffff

#define POOLB 32
#define PT 256
#define PPB (POOLB + NSv / PT)      // 32 pool + 32 pts = 64 blocks
#define PNW (POOLB * PT / 64)       // 128 pool waves -> 64 rows/wave

#define MT 256
#define QT 32
#define MB (NQv / QT)               // 625 (exact)
#define VP 36
#define WS_PTS 8192                 // float offset of float4 pts table in ws (16B aligned)

// ---- prep: pool partials (blocks 0..31) + point table (blocks 32..63)
__global__ __launch_bounds__(PT) void k_prep(const float* __restrict__ cs,
                                             const float* __restrict__ fs7,
                                             const float* __restrict__ wat,
                                             float* __restrict__ ws) {
    int b = blockIdx.x;
    if (b >= POOLB) {               // pts: (-2x,-2y,-2z,|s|^2), one point per thread
        int p = (b - POOLB) * PT + threadIdx.x;
        float x = cs[3 * p], y = cs[3 * p + 1], z = cs[3 * p + 2];
        ((float4*)(ws + WS_PTS))[p] =
            make_float4(-2.f * x, -2.f * y, -2.f * z, fmaf(x, x, fmaf(y, y, z * z)));
        return;
    }
    __shared__ float red[PT / 64][Cv + 1];
    int tid = b * PT + threadIdx.x;
    int wid = tid >> 6, lw = threadIdx.x >> 6, lane = tid & 63, l2 = lane * 2;
    float2 wa = make_float2(0.f, 0.f);
    if (lane < 56) wa = *(const float2*)(wat + l2);
    float gx = 0.f, gy = 0.f, z = 0.f;
    for (int g = 0; g < 16; ++g) {              // 4-row groups: 4 independent shuffle chains
        float2 f[4]; float part[4];
        #pragma unroll
        for (int u = 0; u < 4; ++u) {
            int i = wid + (g * 4 + u) * PNW;
            f[u] = (lane < 56) ? *(const float2*)(fs7 + i * Cv + l2) : make_float2(0.f, 0.f);
            part[u] = f[u].x * wa.x + f[u].y * wa.y;
        }
        #pragma unroll
        for (int off = 32; off; off >>= 1)
            #pragma unroll
            for (int u = 0; u < 4; ++u) part[u] += __shfl_xor(part[u], off, 64);
        #pragma unroll
        for (int u = 0; u < 4; ++u) {
            float p = __expf(part[u]);          // |logit| small, f32-safe
            gx = fmaf(p, f[u].x, gx); gy = fmaf(p, f[u].y, gy); z += p;
        }
    }
    if (lane < 56) { red[lw][l2] = gx; red[lw][l2 + 1] = gy; }
    if (lane == 0) red[lw][Cv] = z;
    __syncthreads();
    int t = threadIdx.x;
    if (t < Cv + 1)
        ws[b * (Cv + 1) + t] = red[0][t] + red[1][t] + red[2][t] + red[3][t];
}

// ---- fused: register-scan (8 queries/lane-wave, 1 distinct point/lane) + MLP GEMM
__global__ __launch_bounds__(MT) void k_fused(
        const float* __restrict__ cq, const float* __restrict__ x7,
        const float* __restrict__ fs, const float* __restrict__ W1,
        const float* __restrict__ gma, const float* __restrict__ bta,
        const float* __restrict__ W2, const float* __restrict__ Wc,
        const float* __restrict__ bc, const float* __restrict__ ws,
        float* __restrict__ out) {
    __shared__ float big[224 * VP];          // V^T -> h2^T
    __shared__ float tT[Cv * VP];            // h1 post-BN-ReLU, transposed
    __shared__ float gate[Cv];
    __shared__ int   qi[QT][3];
    __shared__ float qw[QT][3];

    const float4* __restrict__ ptsg = (const float4*)(ws + WS_PTS);
    int tid = threadIdx.x;
    int q0 = blockIdx.x * QT;

    if (tid < Cv) {                          // gate = sigmoid(pooled mean)
        float st = 0.f, zt = 0.f;
        for (int b = 0; b < POOLB; ++b) {
            st += ws[b * (Cv + 1) + tid];
            zt += ws[b * (Cv + 1) + Cv];
        }
        gate[tid] = 1.0f / (1.0f + __expf(-(st / zt)));
    }

    int lane = tid & 63, widx = tid >> 6;

    // scan: wave widx owns queries q0+widx*8 .. +7; each lane scans 128 distinct
    // points (p = it*64+lane, coalesced dwordx4, zero LDS) updating branchless
    // top-3 state for all 8 queries. e = |s|^2 - 2 q.s (q^2 cancels in softmax).
    float qcx[8], qcy[8], qcz[8];
    #pragma unroll
    for (int r = 0; r < 8; ++r) {
        int q = q0 + widx * 8 + r;
        qcx[r] = cq[3 * q]; qcy[r] = cq[3 * q + 1]; qcz[r] = cq[3 * q + 2];
    }
    float se0[8], se1[8], se2[8]; int sj0[8], sj1[8], sj2[8];
    #pragma unroll
    for (int r = 0; r < 8; ++r) {
        se0[r] = se1[r] = se2[r] = INFF;
        sj0[r] = sj1[r] = sj2[r] = JINF;
    }
    #pragma unroll 2
    for (int it = 0; it < NSv / 64; ++it) {
        int p = it * 64 + lane;
        float4 P = ptsg[p];
        #pragma unroll
        for (int r = 0; r < 8; ++r) {
            float e = fmaf(qcx[r], P.x, fmaf(qcy[r], P.y, fmaf(qcz[r], P.z, P.w)));
            bool c0 = e < se0[r], c1 = e < se1[r], c2 = e < se2[r];
            se2[r] = c1 ? se1[r] : (c2 ? e : se2[r]);
            sj2[r] = c1 ? sj1[r] : (c2 ? p : sj2[r]);
            se1[r] = c0 ? se0[r] : (c1 ? e : se1[r]);
            sj1[r] = c0 ? sj0[r] : (c1 ? p : sj1[r]);
            se0[r] = c0 ? e : se0[r];
            sj0[r] = c0 ? p : sj0[r];
        }
    }
    // per query: exact 3-round pop-merge over 64 sorted lane-lists, lex (e, idx)
    #pragma unroll
    for (int r = 0; r < 8; ++r) {
        float h0 = se0[r], h1 = se1[r], h2 = se2[r];
        int   g0 = sj0[r], g1 = sj1[r], g2 = sj2[r];
        float E[3]; int J[3];
        #pragma unroll
        for (int t = 0; t < 3; ++t) {
            float mv = h0; int mj = g0;
            #pragma unroll
            for (int off = 32; off; off >>= 1) {
                float ov = __shfl_xor(mv, off, 64);
                int   oj = __shfl_xor(mj, off, 64);
                if (ov < mv || (ov == mv && oj < mj)) { mv = ov; mj = oj; }
            }
            E[t] = mv; J[t] = mj;
            bool win = (h0 == mv) && (g0 == mj);
            h0 = win ? h1 : h0; g0 = win ? g1 : g0;
            h1 = win ? h2 : h1; g1 = win ? g2 : g1;
            h2 = win ? INFF : h2; g2 = win ? JINF : g2;
        }
        if (lane == 0) {
            int qq = widx * 8 + r;
            float w1v = __expf(E[0] - E[1]);
            float w2v = __expf(E[0] - E[2]);
            float iw  = 1.0f / (1.0f + w1v + w2v);
            qw[qq][0] = iw; qw[qq][1] = w1v * iw; qw[qq][2] = w2v * iw;
            qi[qq][0] = (J[0] < 0 || J[0] >= NSv) ? 0 : J[0];
            qi[qq][1] = (J[1] < 0 || J[1] >= NSv) ? 0 : J[1];
            qi[qq][2] = (J[2] < 0 || J[2] >= NSv) ? 0 : J[2];
        }
    }
    __syncthreads();

    // build V^T[224][VP]: rows 0..111 = gated x7, rows 112..223 = matched
    {
        int vq = tid >> 3, e8 = tid & 7;
        int gq = q0 + vq;
        int i0 = qi[vq][0], i1 = qi[vq][1], i2 = qi[vq][2];
        float w0 = qw[vq][0], w1v = qw[vq][1], w2v = qw[vq][2];
        #pragma unroll
        for (int r = 0; r < 14; ++r) {
            int k = e8 + (r << 3);
            float m = w0 * fs[i0 * Cv + k] + w1v * fs[i1 * Cv + k] + w2v * fs[i2 * Cv + k];
            big[k * VP + vq] = x7[gq * Cv + k] * gate[k];
            big[(Cv + k) * VP + vq] = m;
        }
    }
    __syncthreads();

    int tx = tid % 28, ty = tid / 28;        // 4 cols x 4 queries per thread, ty<8 active
    int cb = tx * 4, qb = ty * 4;

    // h1 = V @ W1 -> BN affine -> ReLU -> tT[c][q]
    if (ty < 8) {
        float acc[4][4] = {};
        #pragma unroll 4
        for (int k = 0; k < 2 * Cv; ++k) {
            float4 vv = *(const float4*)&big[k * VP + qb];
            float4 ww = *(const float4*)&W1[k * Cv + cb];
            #pragma unroll
            for (int i = 0; i < 4; ++i) {
                float v = (&vv.x)[i];
                acc[i][0] = fmaf(v, ww.x, acc[i][0]);
                acc[i][1] = fmaf(v, ww.y, acc[i][1]);
                acc[i][2] = fmaf(v, ww.z, acc[i][2]);
                acc[i][3] = fmaf(v, ww.w, acc[i][3]);
            }
        }
        #pragma unroll
        for (int j = 0; j < 4; ++j) {
            float g = gma[cb + j], b = bta[cb + j];
            #pragma unroll
            for (int i = 0; i < 4; ++i) {
                float hh = fmaf(acc[i][j], g, b);
                tT[(cb + j) * VP + qb + i] = hh > 0.f ? hh : 0.f;
            }
        }
    }
    __syncthreads();

    // h2 = t @ W2 -> big[c][q] (V^T dead)
    if (ty < 8) {
        float acc[4][4] = {};
        #pragma unroll 4
        for (int k = 0; k < Cv; ++k) {
            float4 vv = *(const float4*)&tT[k * VP + qb];
            float4 ww = *(const float4*)&W2[k * Cv + cb];
            #pragma unroll
            for (int i = 0; i < 4; ++i) {
                float v = (&vv.x)[i];
                acc[i][0] = fmaf(v, ww.x, acc[i][0]);
                acc[i][1] = fmaf(v, ww.y, acc[i][1]);
                acc[i][2] = fmaf(v, ww.z, acc[i][2]);
                acc[i][3] = fmaf(v, ww.w, acc[i][3]);
            }
        }
        #pragma unroll
        for (int j = 0; j < 4; ++j)
            #pragma unroll
            for (int i = 0; i < 4; ++i)
                big[(cb + j) * VP + qb + i] = acc[i][j];
    }
    __syncthreads();

    // out = h2 @ Wc + bc
    {
        int qq = tid & 31, cg = tid >> 5;
        int ob = cg * 3;
        if (ob < CLSv) {
            int nc = CLSv - ob; if (nc > 3) nc = 3;
            float a0 = bc[ob];
            float a1 = (nc > 1) ? bc[ob + 1] : 0.f;
            float a2 = (nc > 2) ? bc[ob + 2] : 0.f;
            #pragma unroll 4
            for (int k = 0; k < Cv; ++k) {
                float hh = big[k * VP + qq];
                a0 = fmaf(hh, Wc[k * CLSv + ob], a0);
                if (nc > 1) a1 = fmaf(hh, Wc[k * CLSv + ob + 1], a1);
                if (nc > 2) a2 = fmaf(hh, Wc[k * CLSv + ob + 2], a2);
            }
            float* o = out + (q0 + qq) * CLSv + ob;
            o[0] = a0;
            if (nc > 1) o[1] = a1;
            if (nc > 2) o[2] = a2;
        }
    }
}

extern "C" void kernel_launch(void* const* d_in, const int* in_sizes, int n_in,
                              void* d_out, int out_size, void* d_ws, size_t ws_size,
                              hipStream_t stream) {
    const float* cq  = (const float*)d_in[0];
    const float* cs  = (const float*)d_in[1];
    const float* x7  = (const float*)d_in[2];
    const float* fs7 = (const float*)d_in[3];
    const float* fs  = (const float*)d_in[4];
    const float* wat = (const float*)d_in[5];
    const float* W1  = (const float*)d_in[6];
    const float* gma = (const float*)d_in[7];
    const float* bta = (const float*)d_in[8];
    const float* W2  = (const float*)d_in[9];
    const float* Wc  = (const float*)d_in[10];
    const float* bc  = (const float*)d_in[11];
    float* ws  = (float*)d_ws;
    float* out = (float*)d_out;

    k_prep<<<PPB, PT, 0, stream>>>(cs, fs7, wat, ws);
    k_fused<<<MB, MT, 0, stream>>>(cq, x7, fs, W1, gma, bta, W2, Wc, bc, ws, out);
}

// Round 7
// 211.483 us; speedup vs baseline: 1.5352x; 1.2167x over previous
//
#include <hip/hip_runtime.h>

#define NQv 20000
#define NSv 8192
#define Cv  112
#define CLSv 20
#define INFF 3.4e38f
#define JINF 0x7fffffff
#define CAP 16

#define POOLB 64
#define PT 256
#define PPB (POOLB + NSv / PT)      // 64 pool + 32 pts = 96 blocks
#define PNW (POOLB * PT / 64)       // 256 pool waves -> 32 rows/wave

#define SB (NQv / 8)                // 2500 scan blocks (8 queries each)
#define MB (NQv / 32)               // 625 mlp blocks (32 queries each)
#define VP 36
#define WS_PTS 8192                 // float offset of float4 pts table (32 KB, 16B aligned)

// ---- prep: pool partials (blocks 0..63) + point table (blocks 64..95)
__global__ __launch_bounds__(PT) void k_prep(const float* __restrict__ cs,
                                             const float* __restrict__ fs7,
                                             const float* __restrict__ wat,
                                             float* __restrict__ ws) {
    int b = blockIdx.x;
    if (b >= POOLB) {               // pts: (-2x,-2y,-2z,|s|^2)
        int p = (b - POOLB) * PT + threadIdx.x;
        float x = cs[3 * p], y = cs[3 * p + 1], z = cs[3 * p + 2];
        ((float4*)(ws + WS_PTS))[p] =
            make_float4(-2.f * x, -2.f * y, -2.f * z, fmaf(x, x, fmaf(y, y, z * z)));
        return;
    }
    __shared__ float red[PT / 64][Cv + 1];
    int tid = b * PT + threadIdx.x;
    int wid = tid >> 6, lw = threadIdx.x >> 6, lane = tid & 63, l2 = lane * 2;
    float2 wa = make_float2(0.f, 0.f);
    if (lane < 56) wa = *(const float2*)(wat + l2);
    float gx = 0.f, gy = 0.f, z = 0.f;
    for (int g = 0; g < 4; ++g) {               // 8-row groups: 8 independent chains
        float2 f[8]; float part[8];
        #pragma unroll
        for (int u = 0; u < 8; ++u) {
            int i = wid + (g * 8 + u) * PNW;
            f[u] = (lane < 56) ? *(const float2*)(fs7 + i * Cv + l2) : make_float2(0.f, 0.f);
            part[u] = f[u].x * wa.x + f[u].y * wa.y;
        }
        #pragma unroll
        for (int off = 32; off; off >>= 1)
            #pragma unroll
            for (int u = 0; u < 8; ++u) part[u] += __shfl_xor(part[u], off, 64);
        #pragma unroll
        for (int u = 0; u < 8; ++u) {
            float p = __expf(part[u]);          // |logit| small, f32-safe
            gx = fmaf(p, f[u].x, gx); gy = fmaf(p, f[u].y, gy); z += p;
        }
    }
    if (lane < 56) { red[lw][l2] = gx; red[lw][l2 + 1] = gy; }
    if (lane == 0) red[lw][Cv] = z;
    __syncthreads();
    int t = threadIdx.x;
    if (t < Cv + 1)
        ws[b * (Cv + 1) + t] = red[0][t] + red[1][t] + red[2][t] + red[3][t];
}

// ---- scan: 8 queries/block, 4 waves x 2048-pt ranges. Phase A: values-only top-3
// (min/med3). Phase B: rescan for e <= E2, exact lex-(e,idx) select. Stash packed
// indices into the query's own d_out row (k_mlp overwrites it later).
__global__ __launch_bounds__(256) void k_scan(const float* __restrict__ cq,
                                              const float* __restrict__ ws,
                                              float* __restrict__ out) {
    __shared__ float wtrip[4][8][3];
    __shared__ float ebound[8];
    __shared__ int   cnt[8];
    __shared__ float candE[8][CAP];
    __shared__ int   candP[8][CAP];
    const float4* __restrict__ pts = (const float4*)(ws + WS_PTS);
    int tid = threadIdx.x, lane = tid & 63, w = tid >> 6;
    int q0 = blockIdx.x * 8;

    float qcx[8], qcy[8], qcz[8];
    #pragma unroll
    for (int r = 0; r < 8; ++r) {
        qcx[r] = cq[3 * (q0 + r)];
        qcy[r] = cq[3 * (q0 + r) + 1];
        qcz[r] = cq[3 * (q0 + r) + 2];
    }
    if (tid < 8) cnt[tid] = 0;

    int base = w * 2048 + lane;
    float a0[8], a1[8], a2[8];
    #pragma unroll
    for (int r = 0; r < 8; ++r) { a0[r] = INFF; a1[r] = INFF; a2[r] = INFF; }

    #pragma unroll 4
    for (int it = 0; it < 32; ++it) {           // phase A: 6 ops/pair
        float4 P = pts[base + it * 64];
        #pragma unroll
        for (int r = 0; r < 8; ++r) {
            float e = fmaf(qcx[r], P.x, fmaf(qcy[r], P.y, fmaf(qcz[r], P.z, P.w)));
            float t1 = __builtin_amdgcn_fmed3f(e, a0[r], a1[r]);
            float t2 = __builtin_amdgcn_fmed3f(e, a1[r], a2[r]);
            a0[r] = fminf(e, a0[r]); a1[r] = t1; a2[r] = t2;
        }
    }
    // in-wave butterfly merge of sorted value-triples
    #pragma unroll
    for (int off = 1; off < 64; off <<= 1) {
        #pragma unroll
        for (int r = 0; r < 8; ++r) {
            float b0 = __shfl_xor(a0[r], off, 64);
            float b1 = __shfl_xor(a1[r], off, 64);
            float b2 = __shfl_xor(a2[r], off, 64);
            float x = fmaxf(a0[r], b0), y = fminf(a1[r], b1);
            float zz = fmaxf(a1[r], b1), u = fminf(a2[r], b2);
            a0[r] = fminf(a0[r], b0);
            a1[r] = fminf(x, y);
            a2[r] = fminf(fminf(fmaxf(x, y), zz), u);
        }
    }
    if (lane == 0) {
        #pragma unroll
        for (int r = 0; r < 8; ++r) {
            wtrip[w][r][0] = a0[r]; wtrip[w][r][1] = a1[r]; wtrip[w][r][2] = a2[r];
        }
    }
    __syncthreads();
    if (tid < 8) {                              // cross-wave merge of 4 triples
        float c0 = wtrip[0][tid][0], c1 = wtrip[0][tid][1], c2 = wtrip[0][tid][2];
        #pragma unroll
        for (int v = 1; v < 4; ++v) {
            float b0 = wtrip[v][tid][0], b1 = wtrip[v][tid][1], b2 = wtrip[v][tid][2];
            float x = fmaxf(c0, b0), y = fminf(c1, b1);
            float zz = fmaxf(c1, b1), u = fminf(c2, b2);
            c0 = fminf(c0, b0);
            c1 = fminf(x, y);
            c2 = fminf(fminf(fmaxf(x, y), zz), u);
        }
        ebound[tid] = c2;
    }
    __syncthreads();

    float eb[8];
    #pragma unroll
    for (int r = 0; r < 8; ++r) eb[r] = ebound[r];
    #pragma unroll 2
    for (int it = 0; it < 32; ++it) {           // phase B: candidate collection
        float4 P = pts[base + it * 64];
        float e[8]; bool h[8]; bool anyh = false;
        #pragma unroll
        for (int r = 0; r < 8; ++r) {
            e[r] = fmaf(qcx[r], P.x, fmaf(qcy[r], P.y, fmaf(qcz[r], P.z, P.w)));
            h[r] = e[r] <= eb[r];
            anyh = anyh || h[r];
        }
        if (__any(anyh)) {
            int p = base + it * 64;
            #pragma unroll
            for (int r = 0; r < 8; ++r)
                if (h[r]) {
                    int s = atomicAdd(&cnt[r], 1);
                    if (s < CAP) { candE[r][s] = e[r]; candP[r][s] = p; }
                }
        }
    }
    __syncthreads();
    if (tid < 8) {                              // exact lex-(e,idx) top-3 of candidates
        int n = cnt[tid]; if (n > CAP) n = CAP;
        float E0 = INFF, E1 = INFF, E2 = INFF;
        int   J0 = JINF, J1 = JINF, J2 = JINF;
        for (int s = 0; s < n; ++s) {
            float e = candE[tid][s]; int p = candP[tid][s];
            bool lt2 = (e < E2) || (e == E2 && p < J2);
            if (lt2) {
                bool lt1 = (e < E1) || (e == E1 && p < J1);
                bool lt0 = (e < E0) || (e == E0 && p < J0);
                E2 = lt1 ? E1 : e;              J2 = lt1 ? J1 : p;
                E1 = lt0 ? E0 : (lt1 ? e : E1); J1 = lt0 ? J0 : (lt1 ? p : J1);
                if (lt0) { E0 = e; J0 = p; }
            }
        }
        J0 = (J0 < 0 || J0 >= NSv) ? 0 : J0;
        J1 = (J1 < 0 || J1 >= NSv) ? 0 : J1;
        J2 = (J2 < 0 || J2 >= NSv) ? 0 : J2;
        int q = q0 + tid;
        ((int*)out)[q * CLSv]     = J0 | (J1 << 16);
        ((int*)out)[q * CLSv + 1] = J2;
    }
}

// ---- mlp: unpack stash, recompute weights, V^T build, batched GEMMs, classifier
__global__ __launch_bounds__(256) void k_mlp(
        const float* __restrict__ cq, const float* __restrict__ x7,
        const float* __restrict__ fs, const float* __restrict__ W1,
        const float* __restrict__ gma, const float* __restrict__ bta,
        const float* __restrict__ W2, const float* __restrict__ Wc,
        const float* __restrict__ bc, const float* __restrict__ ws,
        float* __restrict__ out) {
    __shared__ float big[224 * VP];          // V^T -> h2^T
    __shared__ float tT[Cv * VP];            // h1 post-BN-ReLU
    __shared__ float gate[Cv];
    __shared__ int   qi[32][3];
    __shared__ float qw[32][3];

    const float4* __restrict__ pts = (const float4*)(ws + WS_PTS);
    int tid = threadIdx.x;
    int q0 = blockIdx.x * 32;

    if (tid < Cv) {                          // gate = sigmoid(pooled mean)
        float st = 0.f, zt = 0.f;
        for (int b = 0; b < POOLB; ++b) {
            st += ws[b * (Cv + 1) + tid];
            zt += ws[b * (Cv + 1) + Cv];
        }
        gate[tid] = 1.0f / (1.0f + __expf(-(st / zt)));
    }
    if (tid < 32) {                          // unpack stash + recompute weights
        int q = q0 + tid;
        int A = ((const int*)out)[q * CLSv];
        int B = ((const int*)out)[q * CLSv + 1];
        int J0 = A & 0xFFFF, J1 = (A >> 16) & 0xFFFF, J2 = B;
        J0 = (J0 < 0 || J0 >= NSv) ? 0 : J0;
        J1 = (J1 < 0 || J1 >= NSv) ? 0 : J1;
        J2 = (J2 < 0 || J2 >= NSv) ? 0 : J2;
        float qx = cq[3 * q], qy = cq[3 * q + 1], qz = cq[3 * q + 2];
        float4 P0 = pts[J0], P1 = pts[J1], P2 = pts[J2];
        float e0 = fmaf(qx, P0.x, fmaf(qy, P0.y, fmaf(qz, P0.z, P0.w)));
        float e1 = fmaf(qx, P1.x, fmaf(qy, P1.y, fmaf(qz, P1.z, P1.w)));
        float e2 = fmaf(qx, P2.x, fmaf(qy, P2.y, fmaf(qz, P2.z, P2.w)));
        float w1v = __expf(e0 - e1);
        float w2v = __expf(e0 - e2);
        float iw  = 1.0f / (1.0f + w1v + w2v);
        qw[tid][0] = iw; qw[tid][1] = w1v * iw; qw[tid][2] = w2v * iw;
        qi[tid][0] = J0; qi[tid][1] = J1; qi[tid][2] = J2;
    }
    __syncthreads();

    // build V^T[224][VP]: rows 0..111 = gated x7, rows 112..223 = matched
    {
        int vq = tid >> 3, e8 = tid & 7;
        int gq = q0 + vq;
        int i0 = qi[vq][0], i1 = qi[vq][1], i2 = qi[vq][2];
        float w0 = qw[vq][0], w1v = qw[vq][1], w2v = qw[vq][2];
        #pragma unroll
        for (int r = 0; r < 14; ++r) {
            int k = e8 + (r << 3);
            float m = w0 * fs[i0 * Cv + k] + w1v * fs[i1 * Cv + k] + w2v * fs[i2 * Cv + k];
            big[k * VP + vq] = x7[gq * Cv + k] * gate[k];
            big[(Cv + k) * VP + vq] = m;
        }
    }
    __syncthreads();

    int tx = tid % 28, ty = tid / 28;        // 4 cols x 4 queries per thread
    int cb = tx * 4, qb = ty * 4;

    if (ty < 8) {                            // h1 = V @ W1 -> BN affine -> ReLU
        float acc[4][4] = {};
        #pragma unroll 4
        for (int k = 0; k < 2 * Cv; ++k) {
            float4 vv = *(const float4*)&big[k * VP + qb];
            float4 ww = *(const float4*)&W1[k * Cv + cb];
            #pragma unroll
            for (int i = 0; i < 4; ++i) {
                float v = (&vv.x)[i];
                acc[i][0] = fmaf(v, ww.x, acc[i][0]);
                acc[i][1] = fmaf(v, ww.y, acc[i][1]);
                acc[i][2] = fmaf(v, ww.z, acc[i][2]);
                acc[i][3] = fmaf(v, ww.w, acc[i][3]);
            }
        }
        #pragma unroll
        for (int j = 0; j < 4; ++j) {
            float g = gma[cb + j], b = bta[cb + j];
            #pragma unroll
            for (int i = 0; i < 4; ++i) {
                float hh = fmaf(acc[i][j], g, b);
                tT[(cb + j) * VP + qb + i] = hh > 0.f ? hh : 0.f;
            }
        }
    }
    __syncthreads();

    if (ty < 8) {                            // h2 = t @ W2
        float acc[4][4] = {};
        #pragma unroll 4
        for (int k = 0; k < Cv; ++k) {
            float4 vv = *(const float4*)&tT[k * VP + qb];
            float4 ww = *(const float4*)&W2[k * Cv + cb];
            #pragma unroll
            for (int i = 0; i < 4; ++i) {
                float v = (&vv.x)[i];
                acc[i][0] = fmaf(v, ww.x, acc[i][0]);
                acc[i][1] = fmaf(v, ww.y, acc[i][1]);
                acc[i][2] = fmaf(v, ww.z, acc[i][2]);
                acc[i][3] = fmaf(v, ww.w, acc[i][3]);
            }
        }
        #pragma unroll
        for (int j = 0; j < 4; ++j)
            #pragma unroll
            for (int i = 0; i < 4; ++i)
                big[(cb + j) * VP + qb + i] = acc[i][j];
    }
    __syncthreads();

    // out = h2 @ Wc + bc  (overwrites the stash bytes too)
    {
        int qq = tid & 31, cg = tid >> 5;
        int ob = cg * 3;
        if (ob < CLSv) {
            int nc = CLSv - ob; if (nc > 3) nc = 3;
            float a0v = bc[ob];
            float a1v = (nc > 1) ? bc[ob + 1] : 0.f;
            float a2v = (nc > 2) ? bc[ob + 2] : 0.f;
            #pragma unroll 4
            for (int k = 0; k < Cv; ++k) {
                float hh = big[k * VP + qq];
                a0v = fmaf(hh, Wc[k * CLSv + ob], a0v);
                if (nc > 1) a1v = fmaf(hh, Wc[k * CLSv + ob + 1], a1v);
                if (nc > 2) a2v = fmaf(hh, Wc[k * CLSv + ob + 2], a2v);
            }
            float* o = out + (q0 + qq) * CLSv + ob;
            o[0] = a0v;
            if (nc > 1) o[1] = a1v;
            if (nc > 2) o[2] = a2v;
        }
    }
}

extern "C" void kernel_launch(void* const* d_in, const int* in_sizes, int n_in,
                              void* d_out, int out_size, void* d_ws, size_t ws_size,
                              hipStream_t stream) {
    const float* cq  = (const float*)d_in[0];
    const float* cs  = (const float*)d_in[1];
    const float* x7  = (const float*)d_in[2];
    const float* fs7 = (const float*)d_in[3];
    const float* fs  = (const float*)d_in[4];
    const float* wat = (const float*)d_in[5];
    const float* W1  = (const float*)d_in[6];
    const float* gma = (const float*)d_in[7];
    const float* bta = (const float*)d_in[8];
    const float* W2  = (const float*)d_in[9];
    const float* Wc  = (const float*)d_in[10];
    const float* bc  = (const float*)d_in[11];
    float* ws  = (float*)d_ws;
    float* out = (float*)d_out;

    k_prep<<<PPB, PT, 0, stream>>>(cs, fs7, wat, ws);
    k_scan<<<SB, 256, 0, stream>>>(cq, ws, out);
    k_mlp<<<MB, 256, 0, stream>>>(cq, x7, fs, W1, gma, bta, W2, Wc, bc, ws, out);
}